// Round 13
// baseline (524.564 us; speedup 1.0000x reference)
//
#include <hip/hip_runtime.h>

// CRF forward: B=512 chains, T=1024, L=48.
// Main kernel, 1056 blocks x 256 thr:
//   blocks 0..31    : scan, 1 wave per 16 chains. MFMA step (validated R10/R11)
//                     fed by coalesced global loads from ypT with an 8-row
//                     register ring. NO LDS data path, NO barriers.
//   blocks 32..543  : transpose y_pred -> ypT[g][t][c][l] (3KB rows) in d_ws,
//                     release a per-tile flag (64 rows/tile).
//   blocks 544..1055: point+trans scores, 4 waves split t (validated R6-R11).
// Scan spins on tile flags (device-scope acquire). Scan blocks dispatched
// first and hold only 32 CUs -> producers always schedulable (acyclic).
// Normalizer: damped lag-2 (validated R5-R11). out = 2 commuting atomicAdds.

constexpr int Bb = 512, Tt = 1024, Ll = 48;
constexpr int NC = 16, NSB = Bb / NC;            // 32 scan blocks
constexpr int ROWB = NC * Ll * 4;                // 3072 B per ypT row
constexpr size_t GRPB = (size_t)Tt * ROWB;       // 3 MB per group
constexpr size_t YPT_BYTES = (size_t)NSB * GRPB; // 100,663,296 B
constexpr int NTILE = 16;                        // 64 rows per tile
constexpr int NFLAG = NSB * NTILE;               // 512 flags

#define LOG2E_F 1.44269504088896340736f
#define LN2_F   0.69314718055994530942f

typedef short bf16x8 __attribute__((ext_vector_type(8)));
typedef float f32x4  __attribute__((ext_vector_type(4)));
typedef unsigned int u32x4 __attribute__((ext_vector_type(4)));

__device__ __forceinline__ float fexp2(float x) { return __builtin_amdgcn_exp2f(x); }
__device__ __forceinline__ float flog2(float x) { return __builtin_amdgcn_logf(x); }
__device__ __forceinline__ float rl_f(float v, int l) {
    return __uint_as_float(__builtin_amdgcn_readlane(__float_as_uint(v), (unsigned)l));
}
__device__ __forceinline__ unsigned f2bf(float f) {
    unsigned x = __float_as_uint(f);
    return (x + 0x7FFFu + ((x >> 16) & 1u)) >> 16;
}
__device__ __forceinline__ unsigned pkbf(float lo, float hi) {
    unsigned r;
    asm("v_cvt_pk_bf16_f32 %0, %1, %2" : "=v"(r) : "v"(lo), "v"(hi));
    return r;
}
__device__ __forceinline__ void waitflag(const unsigned* f) {
    while (__hip_atomic_load(f, __ATOMIC_ACQUIRE, __HIP_MEMORY_SCOPE_AGENT) == 0u) {
        __builtin_amdgcn_s_sleep(8);
    }
}

__global__ __launch_bounds__(256)
__attribute__((amdgpu_waves_per_eu(1, 2)))
void crf_fwd_main(const float* __restrict__ y_true,
                  const float* __restrict__ y_pred,
                  const float* __restrict__ trans,
                  float* __restrict__ out,
                  char* __restrict__ wsb)
{
    const int tid = threadIdx.x;
    unsigned* flags = (unsigned*)(wsb + YPT_BYTES);

    // ===================== transpose blocks ================================
    if (blockIdx.x >= NSB && blockIdx.x < NSB + 512) {
        const int tb = blockIdx.x - NSB;
        const int g = tb >> 4, j = tb & 15;
        if (tid < 192) {
            const int c = tid / 12, k = tid % 12;
            const float4* src = (const float4*)(y_pred + (size_t)(NC * g + c) * Tt * Ll);
            float4* dst = (float4*)(wsb + (size_t)g * GRPB);
            #pragma unroll 4
            for (int r = 0; r < 64; ++r) {
                const int t = 64 * j + r;
                dst[(size_t)t * 192 + c * 12 + k] = src[(size_t)t * 12 + k];
            }
        }
        __syncthreads();
        if (tid == 0) {
            __threadfence();
            __hip_atomic_store(&flags[g * 16 + j], 1u,
                               __ATOMIC_RELEASE, __HIP_MEMORY_SCOPE_AGENT);
        }
        return;
    }

    __shared__ float str[Ll * Ll];
    __shared__ float spart[4];

    // ===================== score blocks ====================================
    if (blockIdx.x >= NSB + 512) {
        const int b = blockIdx.x - NSB - 512;
        for (int i = tid; i < Ll * Ll; i += 256) str[i] = trans[i];
        __syncthreads();

        const int wv = tid >> 6, lane = tid & 63;
        const float* __restrict__ yprow = y_pred + (size_t)b * Tt * Ll;
        const float* __restrict__ ytrow = y_true + (size_t)b * Tt * Ll;

        float ps = 0.f, ts = 0.f;
        int labLast = 0;
        if (wv > 0) {                       // seed: label at t = 256*wv - 1
            const float4* r5 = (const float4*)(ytrow + (size_t)(256 * wv - 1) * Ll);
            int lab = 0;
            #pragma unroll
            for (int k = 0; k < 12; ++k) {
                float4 v = r5[k];
                if (v.x > 0.5f) lab = 4 * k + 0;
                if (v.y > 0.5f) lab = 4 * k + 1;
                if (v.z > 0.5f) lab = 4 * k + 2;
                if (v.w > 0.5f) lab = 4 * k + 3;
            }
            labLast = lab;
        }
        for (int k = 0; k < 4; ++k) {
            const int t = 256 * wv + 64 * k + lane;
            const float4* row = (const float4*)(ytrow + (size_t)t * Ll);
            int lab = 0;
            #pragma unroll
            for (int kk = 0; kk < 12; ++kk) {
                float4 v = row[kk];
                if (v.x > 0.5f) lab = 4 * kk + 0;
                if (v.y > 0.5f) lab = 4 * kk + 1;
                if (v.z > 0.5f) lab = 4 * kk + 2;
                if (v.w > 0.5f) lab = 4 * kk + 3;
            }
            ps += yprow[(size_t)t * Ll + lab];
            int labPrev = __shfl_up(lab, 1);
            if (lane == 0) labPrev = labLast;
            if (t > 0) ts += str[labPrev * Ll + lab];
            labLast = __builtin_amdgcn_readlane(lab, 63);
        }
        float acc = ps + ts;
        #pragma unroll
        for (int off = 32; off >= 1; off >>= 1) acc += __shfl_xor(acc, off);
        if (lane == 0) spart[wv] = acc;
        __syncthreads();
        if (tid == 0)
            atomicAdd(&out[b], -((spart[0] + spart[1]) + (spart[2] + spart[3])));
        return;
    }

    // ===================== scan blocks =====================================
    const int g = blockIdx.x;
    for (int i = tid; i < Ll * Ll; i += 256) str[i] = trans[i];
    __syncthreads();
    if (tid >= 64) return;                  // single scan wave

    const int lane = tid;
    const int q = lane >> 4, c = lane & 15;
    const int c4 = 4 * c;

    // A fragments (validated R10/R11): slot (q,i) = Et[g_q(i)][16*beta + c]
    const int r0 = 4 * q;
#define EV(r, beta) fexp2(str[(r) * Ll + 16 * (beta) + c] * LOG2E_F)
#define MKA(beta)                                                              \
    bf16x8 A1_##beta, A2_##beta;                                               \
    { unsigned p0 = f2bf(EV(r0 + 0, beta)) | (f2bf(EV(r0 + 1, beta)) << 16);   \
      unsigned p1 = f2bf(EV(r0 + 2, beta)) | (f2bf(EV(r0 + 3, beta)) << 16);   \
      unsigned p2 = f2bf(EV(16 + r0 + 0, beta)) | (f2bf(EV(16 + r0 + 1, beta)) << 16); \
      unsigned p3 = f2bf(EV(16 + r0 + 2, beta)) | (f2bf(EV(16 + r0 + 3, beta)) << 16); \
      unsigned p4 = f2bf(EV(32 + r0 + 0, beta)) | (f2bf(EV(32 + r0 + 1, beta)) << 16); \
      unsigned p5 = f2bf(EV(32 + r0 + 2, beta)) | (f2bf(EV(32 + r0 + 3, beta)) << 16); \
      u32x4 ta = {p0, p1, p2, p3}; A1_##beta = __builtin_bit_cast(bf16x8, ta); \
      u32x4 tb = {p4, p5, 0u, 0u}; A2_##beta = __builtin_bit_cast(bf16x8, tb); }
    MKA(0) MKA(1) MKA(2)
#undef MKA
#undef EV

    const char* pT = wsb + (size_t)g * GRPB + (size_t)(c * 12 + q) * 16;
    const unsigned* gflag = &flags[g * 16];

    waitflag(&gflag[0]);
    waitflag(&gflag[1]);
    int lastW = 1;

    // init from ypT row 0
    float4 rv0 = *(const float4*)pT;
    float4 rv1 = *(const float4*)(pT + 64);
    float4 rv2 = *(const float4*)(pT + 128);
    float eu00 = fexp2(rv0.x * LOG2E_F), eu01 = fexp2(rv0.y * LOG2E_F);
    float eu02 = fexp2(rv0.z * LOG2E_F), eu03 = fexp2(rv0.w * LOG2E_F);
    float eu10 = fexp2(rv1.x * LOG2E_F), eu11 = fexp2(rv1.y * LOG2E_F);
    float eu12 = fexp2(rv1.z * LOG2E_F), eu13 = fexp2(rv1.w * LOG2E_F);
    float eu20 = fexp2(rv2.x * LOG2E_F), eu21 = fexp2(rv2.y * LOG2E_F);
    float eu22 = fexp2(rv2.z * LOG2E_F), eu23 = fexp2(rv2.w * LOG2E_F);
    float S = 0.f;
    float cUse = 0.5f * LOG2E_F * __uint_as_float(
        (unsigned)__builtin_amdgcn_ds_bpermute(c4, __float_as_uint(rv0.x)));

    // 8-slot register ring
    float4 s0a, s0b, s0c, s1a, s1b, s1c, s2a, s2b, s2c, s3a, s3b, s3c,
           s4a, s4b, s4c, s5a, s5b, s5c, s6a, s6b, s6c, s7a, s7b, s7c;
#define REFILL(J, tn) { const char* rp_ = pT + (size_t)(tn) * ROWB;            \
        s##J##a = *(const float4*)rp_;                                         \
        s##J##b = *(const float4*)(rp_ + 64);                                  \
        s##J##c = *(const float4*)(rp_ + 128); }
    REFILL(0, 1) REFILL(1, 2) REFILL(2, 3) REFILL(3, 4)
    REFILL(4, 5) REFILL(5, 6) REFILL(6, 7) REFILL(7, 8)

#define STEP_CORE(ra, rb, rc)                                                  \
    do {                                                                       \
        unsigned xb0 = pkbf(eu00, eu01), xb1 = pkbf(eu02, eu03);               \
        unsigned xb2 = pkbf(eu10, eu11), xb3 = pkbf(eu12, eu13);               \
        unsigned xb4 = pkbf(eu20, eu21), xb5 = pkbf(eu22, eu23);               \
        u32x4 ub1 = {xb0, xb1, xb2, xb3}; u32x4 ub2 = {xb4, xb5, 0u, 0u};      \
        bf16x8 Bf1 = __builtin_bit_cast(bf16x8, ub1);                          \
        bf16x8 Bf2 = __builtin_bit_cast(bf16x8, ub2);                          \
        int bp = __builtin_amdgcn_ds_bpermute(c4, __float_as_uint(eu00));      \
        float u00 = fexp2(fmaf((ra).x, LOG2E_F, -cUse));                       \
        float u01 = fexp2(fmaf((ra).y, LOG2E_F, -cUse));                       \
        float u02 = fexp2(fmaf((ra).z, LOG2E_F, -cUse));                       \
        float u03 = fexp2(fmaf((ra).w, LOG2E_F, -cUse));                       \
        float u10 = fexp2(fmaf((rb).x, LOG2E_F, -cUse));                       \
        float u11 = fexp2(fmaf((rb).y, LOG2E_F, -cUse));                       \
        float u12 = fexp2(fmaf((rb).z, LOG2E_F, -cUse));                       \
        float u13 = fexp2(fmaf((rb).w, LOG2E_F, -cUse));                       \
        float u20 = fexp2(fmaf((rc).x, LOG2E_F, -cUse));                       \
        float u21 = fexp2(fmaf((rc).y, LOG2E_F, -cUse));                       \
        float u22 = fexp2(fmaf((rc).z, LOG2E_F, -cUse));                       \
        float u23 = fexp2(fmaf((rc).w, LOG2E_F, -cUse));                       \
        float cNew = 0.5f * flog2(__uint_as_float((unsigned)bp));              \
        cNew = fminf(50.f, fmaxf(-50.f, cNew));                                \
        f32x4 zz = {0.f, 0.f, 0.f, 0.f};                                       \
        f32x4 d0 = __builtin_amdgcn_mfma_f32_16x16x32_bf16(A1_0, Bf1, zz, 0, 0, 0); \
        f32x4 g0 = __builtin_amdgcn_mfma_f32_16x16x32_bf16(A2_0, Bf2, zz, 0, 0, 0); \
        f32x4 d1 = __builtin_amdgcn_mfma_f32_16x16x32_bf16(A1_1, Bf1, zz, 0, 0, 0); \
        f32x4 g1 = __builtin_amdgcn_mfma_f32_16x16x32_bf16(A2_1, Bf2, zz, 0, 0, 0); \
        f32x4 d2 = __builtin_amdgcn_mfma_f32_16x16x32_bf16(A1_2, Bf1, zz, 0, 0, 0); \
        f32x4 g2 = __builtin_amdgcn_mfma_f32_16x16x32_bf16(A2_2, Bf2, zz, 0, 0, 0); \
        d0 += g0; d1 += g1; d2 += g2;                                          \
        eu00 = d0[0] * u00; eu01 = d0[1] * u01;                                \
        eu02 = d0[2] * u02; eu03 = d0[3] * u03;                                \
        eu10 = d1[0] * u10; eu11 = d1[1] * u11;                                \
        eu12 = d1[2] * u12; eu13 = d1[3] * u13;                                \
        eu20 = d2[0] * u20; eu21 = d2[1] * u21;                                \
        eu22 = d2[2] * u22; eu23 = d2[3] * u23;                                \
        S += cUse; cUse = cNew;                                                \
    } while (0)

#define STEPR(J, t0)                                                           \
    { STEP_CORE(s##J##a, s##J##b, s##J##c);                                    \
      int tn_ = (t0) + 8 + (J); if (tn_ > Tt - 1) tn_ = Tt - 1;                \
      REFILL(J, tn_) }

    // main: t = 1..1016 (127 iterations of 8)
    for (int t0 = 1; t0 <= 1009; t0 += 8) {
        int need = (t0 + 15) >> 6; if (need > 15) need = 15;
        while (lastW < need) { ++lastW; waitflag(&gflag[lastW]); }
        STEPR(0, t0) STEPR(1, t0) STEPR(2, t0) STEPR(3, t0)
        STEPR(4, t0) STEPR(5, t0) STEPR(6, t0) STEPR(7, t0)
    }
    // tail: t = 1017..1023 (slots 0..6)
    STEP_CORE(s0a, s0b, s0c);
    STEP_CORE(s1a, s1b, s1c);
    STEP_CORE(s2a, s2b, s2c);
    STEP_CORE(s3a, s3b, s3c);
    STEP_CORE(s4a, s4b, s4c);
    STEP_CORE(s5a, s5b, s5c);
    STEP_CORE(s6a, s6b, s6c);
#undef STEPR
#undef STEP_CORE
#undef REFILL

    float sum = ((eu00 + eu01) + (eu02 + eu03))
              + ((eu10 + eu11) + (eu12 + eu13))
              + ((eu20 + eu21) + (eu22 + eu23));
    sum += __shfl_xor(sum, 16);
    sum += __shfl_xor(sum, 32);

    float res = LN2_F * (S + flog2(sum));
    if (lane < NC) atomicAdd(&out[NC * g + lane], res);
}

// ---------------- fallback (R7, known-good 183us) if ws too small ----------
__global__ __launch_bounds__(64)
__attribute__((amdgpu_waves_per_eu(1, 1)))
void crf_fwd_small(const float* __restrict__ y_true,
                   const float* __restrict__ y_pred,
                   const float* __restrict__ trans,
                   float* __restrict__ out)
{
    const int lane = threadIdx.x;
    __shared__ float str[Ll * Ll];

    if (blockIdx.x >= Bb) {
        const int b = blockIdx.x - Bb;
        for (int i = lane; i < Ll * Ll; i += 64) str[i] = trans[i];
        __syncthreads();
        const float* __restrict__ yprow = y_pred + (size_t)b * Tt * Ll;
        const float* __restrict__ ytrow = y_true + (size_t)b * Tt * Ll;
        float ps = 0.f, ts = 0.f;
        int labLast = 0;
        for (int t0 = 0; t0 < Tt; t0 += 64) {
            const int t = t0 + lane;
            const float4* row = (const float4*)(ytrow + (size_t)t * Ll);
            int lab = 0;
            #pragma unroll
            for (int k = 0; k < 12; ++k) {
                float4 v = row[k];
                if (v.x > 0.5f) lab = 4 * k + 0;
                if (v.y > 0.5f) lab = 4 * k + 1;
                if (v.z > 0.5f) lab = 4 * k + 2;
                if (v.w > 0.5f) lab = 4 * k + 3;
            }
            ps += yprow[(size_t)t * Ll + lab];
            int labPrev = __shfl_up(lab, 1);
            if (lane == 0) labPrev = labLast;
            if (t > 0) ts += str[labPrev * Ll + lab];
            labLast = __builtin_amdgcn_readlane(lab, 63);
        }
        float acc = ps + ts;
        #pragma unroll
        for (int off = 32; off >= 1; off >>= 1) acc += __shfl_xor(acc, off);
        if (lane == 0) atomicAdd(&out[b], -acc);
        return;
    }

    const int b = blockIdx.x;
    const int ml = lane < Ll ? lane : (Ll - 1);
    const bool act = lane < Ll;
    for (int i = lane; i < Ll * Ll; i += 64) str[i] = trans[i];
    __syncthreads();
#define MK_E(l) float E##l = fexp2(str[(l) * Ll + ml] * LOG2E_F);
    MK_E(0)  MK_E(1)  MK_E(2)  MK_E(3)  MK_E(4)  MK_E(5)  MK_E(6)  MK_E(7)
    MK_E(8)  MK_E(9)  MK_E(10) MK_E(11) MK_E(12) MK_E(13) MK_E(14) MK_E(15)
    MK_E(16) MK_E(17) MK_E(18) MK_E(19) MK_E(20) MK_E(21) MK_E(22) MK_E(23)
    MK_E(24) MK_E(25) MK_E(26) MK_E(27) MK_E(28) MK_E(29) MK_E(30) MK_E(31)
    MK_E(32) MK_E(33) MK_E(34) MK_E(35) MK_E(36) MK_E(37) MK_E(38) MK_E(39)
    MK_E(40) MK_E(41) MK_E(42) MK_E(43) MK_E(44) MK_E(45) MK_E(46) MK_E(47)
#undef MK_E
    const float* __restrict__ yprow = y_pred + (size_t)b * Tt * Ll;
    float raw0 = yprow[ml];
    float e = fexp2(raw0 * LOG2E_F);
    float S = 0.f;
    float cUse = 0.5f * rl_f(raw0, 0) * LOG2E_F;
#define RLF(l, acc) acc = fmaf(rl_f(e, l), E##l, acc);
#define FSTEP(raw)                                                       \
    do {                                                                 \
        float cNew = 0.5f * flog2(rl_f(e, 0));                           \
        cNew = fminf(50.f, fmaxf(-50.f, cNew));                          \
        float w = fexp2(fmaf((raw), LOG2E_F, -cUse));                    \
        S += cUse;                                                       \
        cUse = cNew;                                                     \
        float a0 = 0.f, a1 = 0.f, a2 = 0.f, a3 = 0.f;                    \
        float a4 = 0.f, a5 = 0.f, a6 = 0.f, a7 = 0.f;                    \
        RLF(0,  a0) RLF(1,  a1) RLF(2,  a2) RLF(3,  a3)                  \
        RLF(4,  a4) RLF(5,  a5) RLF(6,  a6) RLF(7,  a7)                  \
        RLF(8,  a0) RLF(9,  a1) RLF(10, a2) RLF(11, a3)                  \
        RLF(12, a4) RLF(13, a5) RLF(14, a6) RLF(15, a7)                  \
        RLF(16, a0) RLF(17, a1) RLF(18, a2) RLF(19, a3)                  \
        RLF(20, a4) RLF(21, a5) RLF(22, a6) RLF(23, a7)                  \
        RLF(24, a0) RLF(25, a1) RLF(26, a2) RLF(27, a3)                  \
        RLF(28, a4) RLF(29, a5) RLF(30, a6) RLF(31, a7)                  \
        RLF(32, a0) RLF(33, a1) RLF(34, a2) RLF(35, a3)                  \
        RLF(36, a4) RLF(37, a5) RLF(38, a6) RLF(39, a7)                  \
        RLF(40, a0) RLF(41, a1) RLF(42, a2) RLF(43, a3)                  \
        RLF(44, a4) RLF(45, a5) RLF(46, a6) RLF(47, a7)                  \
        e = (((a0 + a1) + (a2 + a3)) + ((a4 + a5) + (a6 + a7))) * w;     \
    } while (0)
    float pfP[4];
    #pragma unroll
    for (int j = 0; j < 4; ++j) pfP[j] = yprow[(1 + j) * Ll + ml];
    for (int t0 = 1; t0 <= Tt - 7; t0 += 4) {
        #pragma unroll
        for (int j = 0; j < 4; ++j) {
            float raw = pfP[j];
            int tn = t0 + j + 4;
            tn = tn < Tt ? tn : (Tt - 1);
            pfP[j] = yprow[tn * Ll + ml];
            FSTEP(raw);
        }
    }
    FSTEP(pfP[0]); FSTEP(pfP[1]); FSTEP(pfP[2]);
#undef FSTEP
#undef RLF
    float es = act ? e : 0.f;
    #pragma unroll
    for (int off = 32; off >= 1; off >>= 1) es += __shfl_xor(es, off);
    if (lane == 0) atomicAdd(&out[b], LN2_F * (S + flog2(es)));
}

extern "C" void kernel_launch(void* const* d_in, const int* in_sizes, int n_in,
                              void* d_out, int out_size, void* d_ws, size_t ws_size,
                              hipStream_t stream) {
    const float* y_true = (const float*)d_in[0];
    const float* y_pred = (const float*)d_in[1];
    const float* trans  = (const float*)d_in[2];
    float* out = (float*)d_out;

    hipMemsetAsync(d_out, 0, (size_t)out_size * sizeof(float), stream);
    const size_t need = YPT_BYTES + (size_t)NFLAG * sizeof(unsigned);
    if (ws_size >= need) {
        hipMemsetAsync((char*)d_ws + YPT_BYTES, 0, NFLAG * sizeof(unsigned), stream);
        crf_fwd_main<<<NSB + 512 + Bb, 256, 0, stream>>>(
            y_true, y_pred, trans, out, (char*)d_ws);
    } else {
        crf_fwd_small<<<2 * Bb, 64, 0, stream>>>(y_true, y_pred, trans, out);
    }
}

// Round 14
// 248.392 us; speedup vs baseline: 2.1118x; 2.1118x over previous
//
#include <hip/hip_runtime.h>

// CRF forward: B=512 chains, T=1024, L=48.
// ONE kernel, 256 blocks x 256 thr, waves_per_eu(1,1) -> 1 block per CU.
//   blocks 0..127  : wave 0 = MFMA scan of 4 chains (waves 1-3 exit; the CU
//                    stays dedicated: a 4-wave block can't fit in 3 free EUs).
//                    Direct y_pred loads, 3x256B/step, zero overfetch,
//                    8-row register ring. No LDS data path, no barriers.
//   blocks 128..255: 4 score waves, one chain each (validated R6 loop).
// Scan step = R10/R11/R12-validated MFMA math (absmax 0.0 x3): 6 cvt_pk,
// 6 x mfma_f32_16x16x32_bf16 (3 m-blocks x 2 k-chunks), damped lag-2
// normalizer via one ds_bpermute. B cols 4..15 are garbage chains - garbage
// stays confined to its own column; loads clamped to chain 3.
// out[b] = scan atomicAdd + score atomicAdd onto memset 0 (2 commuting adds).

constexpr int Bb = 512, Tt = 1024, Ll = 48;
constexpr int NCW = 4;                 // chains per scan wave
constexpr int NSB = Bb / NCW;          // 128 scan blocks

#define LOG2E_F 1.44269504088896340736f
#define LN2_F   0.69314718055994530942f

typedef short bf16x8 __attribute__((ext_vector_type(8)));
typedef float f32x4  __attribute__((ext_vector_type(4)));
typedef unsigned int u32x4 __attribute__((ext_vector_type(4)));

__device__ __forceinline__ float fexp2(float x) { return __builtin_amdgcn_exp2f(x); }
__device__ __forceinline__ float flog2(float x) { return __builtin_amdgcn_logf(x); }
__device__ __forceinline__ unsigned f2bf(float f) {
    unsigned x = __float_as_uint(f);
    return (x + 0x7FFFu + ((x >> 16) & 1u)) >> 16;
}
__device__ __forceinline__ unsigned pkbf(float lo, float hi) {
    unsigned r;
    asm("v_cvt_pk_bf16_f32 %0, %1, %2" : "=v"(r) : "v"(lo), "v"(hi));
    return r;
}

__global__ __launch_bounds__(256)
__attribute__((amdgpu_waves_per_eu(1, 1)))
void crf_fwd_kernel(const float* __restrict__ y_true,
                    const float* __restrict__ y_pred,
                    const float* __restrict__ trans,
                    float* __restrict__ out)
{
    const int tid = threadIdx.x;
    __shared__ float str[Ll * Ll];
    for (int i = tid; i < Ll * Ll; i += 256) str[i] = trans[i];
    __syncthreads();

    if (blockIdx.x >= NSB) {
        // ============ score block: 4 waves, chain per wave =================
        const int wv = tid >> 6, lane = tid & 63;
        const int b = NCW * (blockIdx.x - NSB) + wv;
        const float* __restrict__ yprow = y_pred + (size_t)b * Tt * Ll;
        const float* __restrict__ ytrow = y_true + (size_t)b * Tt * Ll;

        float ps = 0.f, ts = 0.f;
        int labLast = 0;
        for (int t0 = 0; t0 < Tt; t0 += 64) {
            const int t = t0 + lane;
            const float4* row = (const float4*)(ytrow + (size_t)t * Ll);
            int lab = 0;
            #pragma unroll
            for (int k = 0; k < 12; ++k) {
                float4 v = row[k];
                if (v.x > 0.5f) lab = 4 * k + 0;
                if (v.y > 0.5f) lab = 4 * k + 1;
                if (v.z > 0.5f) lab = 4 * k + 2;
                if (v.w > 0.5f) lab = 4 * k + 3;
            }
            ps += yprow[(size_t)t * Ll + lab];
            int labPrev = __shfl_up(lab, 1);
            if (lane == 0) labPrev = labLast;
            if (t > 0) ts += str[labPrev * Ll + lab];
            labLast = __builtin_amdgcn_readlane(lab, 63);
        }
        float acc = ps + ts;
        #pragma unroll
        for (int off = 32; off >= 1; off >>= 1) acc += __shfl_xor(acc, off);
        if (lane == 0) atomicAdd(&out[b], -acc);
        return;
    }

    // ============ scan block: wave 0 only, chains 4g..4g+3 =================
    if (tid >= 64) return;                    // waves 1-3 exit; CU stays ours
    const int lane = tid;
    const int g = blockIdx.x;
    const int q = lane >> 4, c = lane & 15;
    const int c4 = 4 * c;
    const int cc = c < NCW ? c : (NCW - 1);   // clamped chain for loads

    // A fragments (validated R10-R12): slot (q,i) = Et[g_q(i)][16*beta + c]
    const int r0 = 4 * q;
#define EV(r, beta) fexp2(str[(r) * Ll + 16 * (beta) + c] * LOG2E_F)
#define MKA(beta)                                                              \
    bf16x8 A1_##beta, A2_##beta;                                               \
    { unsigned p0 = f2bf(EV(r0 + 0, beta)) | (f2bf(EV(r0 + 1, beta)) << 16);   \
      unsigned p1 = f2bf(EV(r0 + 2, beta)) | (f2bf(EV(r0 + 3, beta)) << 16);   \
      unsigned p2 = f2bf(EV(16 + r0 + 0, beta)) | (f2bf(EV(16 + r0 + 1, beta)) << 16); \
      unsigned p3 = f2bf(EV(16 + r0 + 2, beta)) | (f2bf(EV(16 + r0 + 3, beta)) << 16); \
      unsigned p4 = f2bf(EV(32 + r0 + 0, beta)) | (f2bf(EV(32 + r0 + 1, beta)) << 16); \
      unsigned p5 = f2bf(EV(32 + r0 + 2, beta)) | (f2bf(EV(32 + r0 + 3, beta)) << 16); \
      u32x4 ta = {p0, p1, p2, p3}; A1_##beta = __builtin_bit_cast(bf16x8, ta); \
      u32x4 tb = {p4, p5, 0u, 0u}; A2_##beta = __builtin_bit_cast(bf16x8, tb); }
    MKA(0) MKA(1) MKA(2)
#undef MKA
#undef EV

    // per-lane base pointers: chain cc, m-chunks 4q + 16*beta
    const float* baseP = y_pred + (size_t)(NCW * g + cc) * Tt * Ll;
    const float* p0 = baseP + 4 * q;
    const float* p1 = baseP + 16 + 4 * q;
    const float* p2 = baseP + 32 + 4 * q;

    // t = 0 init
    float4 rv0 = *(const float4*)p0;
    float4 rv1 = *(const float4*)p1;
    float4 rv2 = *(const float4*)p2;
    float eu00 = fexp2(rv0.x * LOG2E_F), eu01 = fexp2(rv0.y * LOG2E_F);
    float eu02 = fexp2(rv0.z * LOG2E_F), eu03 = fexp2(rv0.w * LOG2E_F);
    float eu10 = fexp2(rv1.x * LOG2E_F), eu11 = fexp2(rv1.y * LOG2E_F);
    float eu12 = fexp2(rv1.z * LOG2E_F), eu13 = fexp2(rv1.w * LOG2E_F);
    float eu20 = fexp2(rv2.x * LOG2E_F), eu21 = fexp2(rv2.y * LOG2E_F);
    float eu22 = fexp2(rv2.z * LOG2E_F), eu23 = fexp2(rv2.w * LOG2E_F);
    float S = 0.f;
    // raw[0] of chain c lives in lane (0,c).rv0.x -> bpermute idx 4c
    float cUse = 0.5f * LOG2E_F * __uint_as_float(
        (unsigned)__builtin_amdgcn_ds_bpermute(c4, __float_as_uint(rv0.x)));

    // 8-slot register ring (rows t = 1..8)
    float4 s0a, s0b, s0c, s1a, s1b, s1c, s2a, s2b, s2c, s3a, s3b, s3c,
           s4a, s4b, s4c, s5a, s5b, s5c, s6a, s6b, s6c, s7a, s7b, s7c;
#define REFILL(J, tn) { const size_t o_ = (size_t)(tn) * Ll;                   \
        s##J##a = *(const float4*)(p0 + o_);                                   \
        s##J##b = *(const float4*)(p1 + o_);                                   \
        s##J##c = *(const float4*)(p2 + o_); }
    REFILL(0, 1) REFILL(1, 2) REFILL(2, 3) REFILL(3, 4)
    REFILL(4, 5) REFILL(5, 6) REFILL(6, 7) REFILL(7, 8)

#define STEP_CORE(ra, rb, rc)                                                  \
    do {                                                                       \
        unsigned xb0 = pkbf(eu00, eu01), xb1 = pkbf(eu02, eu03);               \
        unsigned xb2 = pkbf(eu10, eu11), xb3 = pkbf(eu12, eu13);               \
        unsigned xb4 = pkbf(eu20, eu21), xb5 = pkbf(eu22, eu23);               \
        u32x4 ub1 = {xb0, xb1, xb2, xb3}; u32x4 ub2 = {xb4, xb5, 0u, 0u};      \
        bf16x8 Bf1 = __builtin_bit_cast(bf16x8, ub1);                          \
        bf16x8 Bf2 = __builtin_bit_cast(bf16x8, ub2);                          \
        int bp = __builtin_amdgcn_ds_bpermute(c4, __float_as_uint(eu00));      \
        float u00 = fexp2(fmaf((ra).x, LOG2E_F, -cUse));                       \
        float u01 = fexp2(fmaf((ra).y, LOG2E_F, -cUse));                       \
        float u02 = fexp2(fmaf((ra).z, LOG2E_F, -cUse));                       \
        float u03 = fexp2(fmaf((ra).w, LOG2E_F, -cUse));                       \
        float u10 = fexp2(fmaf((rb).x, LOG2E_F, -cUse));                       \
        float u11 = fexp2(fmaf((rb).y, LOG2E_F, -cUse));                       \
        float u12 = fexp2(fmaf((rb).z, LOG2E_F, -cUse));                       \
        float u13 = fexp2(fmaf((rb).w, LOG2E_F, -cUse));                       \
        float u20 = fexp2(fmaf((rc).x, LOG2E_F, -cUse));                       \
        float u21 = fexp2(fmaf((rc).y, LOG2E_F, -cUse));                       \
        float u22 = fexp2(fmaf((rc).z, LOG2E_F, -cUse));                       \
        float u23 = fexp2(fmaf((rc).w, LOG2E_F, -cUse));                       \
        float cNew = 0.5f * flog2(__uint_as_float((unsigned)bp));              \
        cNew = fminf(50.f, fmaxf(-50.f, cNew));                                \
        f32x4 zz = {0.f, 0.f, 0.f, 0.f};                                       \
        f32x4 d0 = __builtin_amdgcn_mfma_f32_16x16x32_bf16(A1_0, Bf1, zz, 0, 0, 0); \
        f32x4 g0 = __builtin_amdgcn_mfma_f32_16x16x32_bf16(A2_0, Bf2, zz, 0, 0, 0); \
        f32x4 d1 = __builtin_amdgcn_mfma_f32_16x16x32_bf16(A1_1, Bf1, zz, 0, 0, 0); \
        f32x4 g1 = __builtin_amdgcn_mfma_f32_16x16x32_bf16(A2_1, Bf2, zz, 0, 0, 0); \
        f32x4 d2 = __builtin_amdgcn_mfma_f32_16x16x32_bf16(A1_2, Bf1, zz, 0, 0, 0); \
        f32x4 g2 = __builtin_amdgcn_mfma_f32_16x16x32_bf16(A2_2, Bf2, zz, 0, 0, 0); \
        d0 += g0; d1 += g1; d2 += g2;                                          \
        eu00 = d0[0] * u00; eu01 = d0[1] * u01;                                \
        eu02 = d0[2] * u02; eu03 = d0[3] * u03;                                \
        eu10 = d1[0] * u10; eu11 = d1[1] * u11;                                \
        eu12 = d1[2] * u12; eu13 = d1[3] * u13;                                \
        eu20 = d2[0] * u20; eu21 = d2[1] * u21;                                \
        eu22 = d2[2] * u22; eu23 = d2[3] * u23;                                \
        S += cUse; cUse = cNew;                                                \
    } while (0)

#define STEPR(J, t0)                                                           \
    { STEP_CORE(s##J##a, s##J##b, s##J##c);                                    \
      int tn_ = (t0) + 8 + (J); if (tn_ > Tt - 1) tn_ = Tt - 1;                \
      REFILL(J, tn_) }

    // main: t = 1..1016 (127 x 8), tail t = 1017..1023
    for (int t0 = 1; t0 <= 1009; t0 += 8) {
        STEPR(0, t0) STEPR(1, t0) STEPR(2, t0) STEPR(3, t0)
        STEPR(4, t0) STEPR(5, t0) STEPR(6, t0) STEPR(7, t0)
    }
    STEP_CORE(s0a, s0b, s0c);
    STEP_CORE(s1a, s1b, s1c);
    STEP_CORE(s2a, s2b, s2c);
    STEP_CORE(s3a, s3b, s3c);
    STEP_CORE(s4a, s4b, s4c);
    STEP_CORE(s5a, s5b, s5c);
    STEP_CORE(s6a, s6b, s6c);
#undef STEPR
#undef STEP_CORE
#undef REFILL

    // epilogue: per-chain sum over 48 m's
    float sum = ((eu00 + eu01) + (eu02 + eu03))
              + ((eu10 + eu11) + (eu12 + eu13))
              + ((eu20 + eu21) + (eu22 + eu23));
    sum += __shfl_xor(sum, 16);
    sum += __shfl_xor(sum, 32);

    float res = LN2_F * (S + flog2(sum));
    if (lane < NCW) atomicAdd(&out[NCW * g + lane], res);
}

extern "C" void kernel_launch(void* const* d_in, const int* in_sizes, int n_in,
                              void* d_out, int out_size, void* d_ws, size_t ws_size,
                              hipStream_t stream) {
    const float* y_true = (const float*)d_in[0];
    const float* y_pred = (const float*)d_in[1];
    const float* trans  = (const float*)d_in[2];
    float* out = (float*)d_out;

    hipMemsetAsync(d_out, 0, (size_t)out_size * sizeof(float), stream);
    crf_fwd_kernel<<<NSB + NSB, 256, 0, stream>>>(y_true, y_pred, trans, out);
}